// Round 10
// baseline (578.231 us; speedup 1.0000x reference)
//
#include <hip/hip_runtime.h>
#include <math.h>

// ---- problem constants ----
#define B_      32
#define HH      56
#define WW_     56
#define DIM     192
#define WS_     7
#define SHIFT_  3
#define HEADS   6
#define HDIM    32
#define NTOK    49          // WS*WS
#define NWIN    64          // (H/WS)*(W/WS)
#define HIDDEN  768
#define MTOT    (B_*HH*WW_) // 100352 tokens
#define EPS_    1e-5f
#define SCALE_  0.17677669529663687f  // 1/sqrt(32)

// fused-attention LDS strides (u16 units) — round-0 proven values (measured 161 us)
#define ALD 200  // Ash/Qsh/Ksh/Osh row stride (64 rows)
#define PLD 40   // P row stride (per-head 64 rows)
#define VLD 72   // Vt row stride (192 rows)

// fused-MLP geometry (round-6 proven): 64 rows/block, quarter-H slab in LDS
#define MROWS 64
#define HLDQ  200  // H quarter-slab row stride (192 + 8 pad); 400 B -> 2-way banks

typedef unsigned short u16;
typedef __attribute__((ext_vector_type(8))) __bf16 bf16x8;
typedef __attribute__((ext_vector_type(4))) float f32x4;

__device__ __forceinline__ float bf2f(u16 u) {
    union { unsigned int i; float f; } c; c.i = ((unsigned int)u) << 16; return c.f;
}
__device__ __forceinline__ u16 f2bf(float f) {
    union { float f; unsigned int i; } c; c.f = f;
    unsigned int x = c.i;
    return (u16)((x + 0x7FFFu + ((x >> 16) & 1u)) >> 16);  // RNE (finite values)
}

__device__ __forceinline__ float wave_sum(float v) {
    #pragma unroll
    for (int off = 32; off > 0; off >>= 1) v += __shfl_xor(v, off, 64);
    return v;
}

// ====== merged prep: 4 weight transposes + bias/mask table + LN1 in ONE launch ======
// Block ranges: [0,108) qkv, [108,144) proj, [144,288) fc1, [288,432) fc2,
// [432,6576) tbl, [6576,31664) ln1+roll+window. Branch is block-uniform.
__global__ __launch_bounds__(256) void prep_kernel(
        const float* __restrict__ qkv_w, const float* __restrict__ proj_w,
        const float* __restrict__ fc1_w, const float* __restrict__ fc2_w,
        u16* __restrict__ qkv_wT, u16* __restrict__ proj_wT,
        u16* __restrict__ fc1_wT, u16* __restrict__ fc2_wT,
        const float* __restrict__ rel_table, const float* __restrict__ mask,
        float* __restrict__ tbl,
        const float* __restrict__ x, const float* __restrict__ g1,
        const float* __restrict__ b1, u16* __restrict__ hwin) {
    __shared__ float t[32][33];
    int b = blockIdx.x;
    if (b >= 6576) {
        // ---- LN1 + roll(-3,-3) + window partition (fp32 in, bf16 out) ----
        int row  = (b - 6576) * 4 + (threadIdx.x >> 6);
        int lane = threadIdx.x & 63;
        int win = row / NTOK;
        int n   = row - win * NTOK;
        int bb  = win >> 6;
        int wl  = win & 63;
        int hi  = (wl >> 3) * WS_ + n / WS_;
        int hj  = (wl & 7) * WS_ + n % WS_;
        int sh = hi + SHIFT_; if (sh >= HH) sh -= HH;
        int sw = hj + SHIFT_; if (sw >= WW_) sw -= WW_;
        const float* xr = x + ((size_t)(bb * HH * WW_ + sh * WW_ + sw)) * DIM;
        float v0 = xr[lane], v1 = xr[lane + 64], v2 = xr[lane + 128];
        float s  = wave_sum(v0 + v1 + v2);
        float sq = wave_sum(v0 * v0 + v1 * v1 + v2 * v2);
        float mu  = s * (1.0f / DIM);
        float var = sq * (1.0f / DIM) - mu * mu;
        float r = rsqrtf(var + EPS_);
        u16* orow = hwin + (size_t)row * DIM;
        orow[lane]       = f2bf((v0 - mu) * r * g1[lane]       + b1[lane]);
        orow[lane + 64]  = f2bf((v1 - mu) * r * g1[lane + 64]  + b1[lane + 64]);
        orow[lane + 128] = f2bf((v2 - mu) * r * g1[lane + 128] + b1[lane + 128]);
        return;
    }
    if (b >= 432) {
        // ---- fused bias+mask table: tbl[((wl*6+head)*64+qi)*64+kj], pads = -1e30 ----
        int idx = (b - 432) * 256 + threadIdx.x;   // < 64*6*4096
        int kj   = idx & 63;
        int qi   = (idx >> 6) & 63;
        int head = (idx >> 12) % 6;
        int wl   = idx / (6 << 12);
        float v;
        if (qi < NTOK && kj < NTOK) {
            int qr = qi / WS_, qc = qi % WS_;
            int kr = kj / WS_, kc = kj % WS_;
            int ri = (qr - kr + 6) * 13 + (qc - kc + 6);
            v = rel_table[ri * HEADS + head] + mask[((size_t)wl * NTOK + qi) * NTOK + kj];
        } else {
            v = -1e30f;
        }
        tbl[idx] = v;
        return;
    }
    const float* W; u16* Wt; int K, N, tb;
    if (b < 108)      { W = qkv_w;  Wt = qkv_wT;  K = DIM;    N = 3 * DIM; tb = b; }
    else if (b < 144) { W = proj_w; Wt = proj_wT; K = DIM;    N = DIM;     tb = b - 108; }
    else if (b < 288) { W = fc1_w;  Wt = fc1_wT;  K = DIM;    N = HIDDEN;  tb = b - 144; }
    else              { W = fc2_w;  Wt = fc2_wT;  K = HIDDEN; N = DIM;     tb = b - 288; }
    // ---- tiled transpose: Wt[n*K+k] = bf16(W[k*N+n]) ----
    int nt32 = N >> 5;
    int bx = tb % nt32;      // n-tile
    int by = tb / nt32;      // k-tile
    int tx = threadIdx.x & 31, ty = threadIdx.x >> 5;   // ty in [0,8)
    #pragma unroll
    for (int i = 0; i < 4; i++)
        t[ty + i * 8][tx] = W[(size_t)(by * 32 + ty + i * 8) * N + bx * 32 + tx];
    __syncthreads();
    #pragma unroll
    for (int i = 0; i < 4; i++)
        Wt[(size_t)(bx * 32 + ty + i * 8) * K + by * 32 + tx] = f2bf(t[tx][ty + i * 8]);
}

// ---------------- LN2: fp32 in (residual stream = out buffer), bf16 out ----------------
__global__ __launch_bounds__(256) void ln2_kernel(
        const float* __restrict__ x, const float* __restrict__ g,
        const float* __restrict__ b, u16* __restrict__ out) {
    int row  = blockIdx.x * 4 + (threadIdx.x >> 6);
    int lane = threadIdx.x & 63;
    const float* xr = x + (size_t)row * DIM;
    float v0 = xr[lane], v1 = xr[lane + 64], v2 = xr[lane + 128];
    float s  = wave_sum(v0 + v1 + v2);
    float sq = wave_sum(v0 * v0 + v1 * v1 + v2 * v2);
    float mu  = s * (1.0f / DIM);
    float var = sq * (1.0f / DIM) - mu * mu;
    float r = rsqrtf(var + EPS_);
    u16* orow = out + (size_t)row * DIM;
    orow[lane]       = f2bf((v0 - mu) * r * g[lane]       + b[lane]);
    orow[lane + 64]  = f2bf((v1 - mu) * r * g[lane + 64]  + b[lane + 64]);
    orow[lane + 128] = f2bf((v2 - mu) * r * g[lane + 128] + b[lane + 128]);
}

// ================= fused window attention: QKV + attn + proj + residual =================
// One block per window (2048), 384 threads = 6 waves = 6 heads.  [measured 161-175 us]
// LDS: R1 [0,15360) u16: Ash/Qsh/Ksh (64xALD) -> P (6 x 64xPLD) -> Osh (64xALD)
//      Vt [15360, 29184): 192 x VLD
// NOTE: no min-waves launch bound (forced 5/EU -> VGPR 48 -> spill disaster, round 2).
// NOTE: LN1/LN2 must NOT be fused in as wave-per-row epilogues (rounds 1 & 5: +60-90 us).
// NOTE: occupancy is register-bound (VGPR+acc); LDS trim to 53760 did not raise it (r3).
// FROZEN (round-6 form).
__global__ __launch_bounds__(384) void fused_attn_kernel(
        const u16* __restrict__ hwin, const u16* __restrict__ qkv_wT,
        const float* __restrict__ qkv_b, const u16* __restrict__ proj_wT,
        const float* __restrict__ proj_b, const float* __restrict__ tbl,
        const float* __restrict__ x, float* __restrict__ x1) {
    __shared__ u16 sm[29184];
    u16* R1 = sm;
    u16* Vt = sm + 15360;

    const int tid  = threadIdx.x;
    const int w    = tid >> 6;       // head
    const int lane = tid & 63;
    const int lrow = lane & 15, lq = lane >> 4;
    const int win  = blockIdx.x;
    const int wl   = win & 63, bb = win >> 6;

    // ---- phase 0: stage LN1 window rows (49x192, zero-pad to 64) ----
    {
        const uint4* src = (const uint4*)(hwin + (size_t)win * NTOK * DIM);
        uint4 z; z.x = z.y = z.z = z.w = 0u;
        #pragma unroll
        for (int it = 0; it < 4; it++) {
            int i = tid + it * 384;          // < 1536 = 64*24
            int row = i / 24, c = i - row * 24;
            uint4 v = (row < NTOK) ? src[row * 24 + c] : z;
            *(uint4*)&R1[row * ALD + c * 8] = v;
        }
    }
    __syncthreads();

    // ---- phase 1: QKV projection for this head (W streamed from L2) ----
    f32x4 acc[3][4][2];
    #pragma unroll
    for (int o = 0; o < 3; o++)
        #pragma unroll
        for (int mt = 0; mt < 4; mt++)
            #pragma unroll
            for (int nt = 0; nt < 2; nt++) acc[o][mt][nt] = (f32x4){0.f, 0.f, 0.f, 0.f};

    const u16* bcol[3][2];
    #pragma unroll
    for (int o = 0; o < 3; o++)
        #pragma unroll
        for (int nt = 0; nt < 2; nt++)
            bcol[o][nt] = qkv_wT + (size_t)(o * DIM + w * 32 + nt * 16 + lrow) * DIM + lq * 8;

    #pragma unroll
    for (int ks = 0; ks < 6; ks++) {
        bf16x8 aF[4];
        #pragma unroll
        for (int mt = 0; mt < 4; mt++)
            aF[mt] = *(const bf16x8*)&R1[(mt * 16 + lrow) * ALD + ks * 32 + lq * 8];
        bf16x8 bF[3][2];
        #pragma unroll
        for (int o = 0; o < 3; o++)
            #pragma unroll
            for (int nt = 0; nt < 2; nt++)
                bF[o][nt] = *(const bf16x8*)(bcol[o][nt] + ks * 32);
        __builtin_amdgcn_s_setprio(1);
        #pragma unroll
        for (int o = 0; o < 3; o++)
            #pragma unroll
            for (int mt = 0; mt < 4; mt++)
                #pragma unroll
                for (int nt = 0; nt < 2; nt++)
                    acc[o][mt][nt] = __builtin_amdgcn_mfma_f32_16x16x32_bf16(
                        aF[mt], bF[o][nt], acc[o][mt][nt], 0, 0, 0);
        __builtin_amdgcn_s_setprio(0);
    }
    // biases
    float bias_[3][2];
    #pragma unroll
    for (int o = 0; o < 3; o++)
        #pragma unroll
        for (int nt = 0; nt < 2; nt++)
            bias_[o][nt] = qkv_b[o * DIM + w * 32 + nt * 16 + lrow];
    #pragma unroll
    for (int o = 0; o < 3; o++)
        #pragma unroll
        for (int mt = 0; mt < 4; mt++)
            #pragma unroll
            for (int nt = 0; nt < 2; nt++)
                #pragma unroll
                for (int r = 0; r < 4; r++) acc[o][mt][nt][r] += bias_[o][nt];

    __syncthreads();   // Ash dead; R1 becomes Q/K staging (wave-local col stripes)

    // ---- phase 2: stage Q (C-layout -> A-frag), then K (-> B-frag), then V^T ----
    #pragma unroll
    for (int mt = 0; mt < 4; mt++)
        #pragma unroll
        for (int nt = 0; nt < 2; nt++)
            #pragma unroll
            for (int r = 0; r < 4; r++)
                R1[(mt * 16 + lq * 4 + r) * ALD + w * 32 + nt * 16 + lrow] =
                    f2bf(acc[0][mt][nt][r]);
    bf16x8 qf[4];
    #pragma unroll
    for (int mt = 0; mt < 4; mt++)
        qf[mt] = *(const bf16x8*)&R1[(mt * 16 + lrow) * ALD + w * 32 + lq * 8];

    #pragma unroll
    for (int mt = 0; mt < 4; mt++)
        #pragma unroll
        for (int nt = 0; nt < 2; nt++)
            #pragma unroll
            for (int r = 0; r < 4; r++)
                R1[(mt * 16 + lq * 4 + r) * ALD + w * 32 + nt * 16 + lrow] =
                    f2bf(acc[1][mt][nt][r]);
    bf16x8 kf[4];
    #pragma unroll
    for (int nt = 0; nt < 4; nt++)
        kf[nt] = *(const bf16x8*)&R1[(nt * 16 + lrow) * ALD + w * 32 + lq * 8];

    #pragma unroll
    for (int mt = 0; mt < 4; mt++)
        #pragma unroll
        for (int nt = 0; nt < 2; nt++)
            #pragma unroll
            for (int r = 0; r < 4; r++)
                Vt[(w * 32 + nt * 16 + lrow) * VLD + mt * 16 + lq * 4 + r] =
                    f2bf(acc[2][mt][nt][r]);

    // ---- phase 3: S = Q.K^T (16 mfma), softmax in registers ----
    f32x4 sc[4][4];
    __builtin_amdgcn_s_setprio(1);
    #pragma unroll
    for (int mt = 0; mt < 4; mt++)
        #pragma unroll
        for (int nt = 0; nt < 4; nt++) {
            f32x4 z = (f32x4){0.f, 0.f, 0.f, 0.f};
            sc[mt][nt] = __builtin_amdgcn_mfma_f32_16x16x32_bf16(qf[mt], kf[nt], z, 0, 0, 0);
        }
    __builtin_amdgcn_s_setprio(0);
    const float* tb = tbl + (((size_t)wl * HEADS + w) << 12);
    float inv[4][4];
    #pragma unroll
    for (int mt = 0; mt < 4; mt++)
        #pragma unroll
        for (int r = 0; r < 4; r++) {
            int qi = mt * 16 + lq * 4 + r;
            float mx = -3.0e38f;
            #pragma unroll
            for (int nt = 0; nt < 4; nt++) {
                float s = sc[mt][nt][r] * SCALE_ + tb[(qi << 6) + nt * 16 + lrow];
                sc[mt][nt][r] = s;
                mx = fmaxf(mx, s);
            }
            #pragma unroll
            for (int off = 8; off > 0; off >>= 1) mx = fmaxf(mx, __shfl_xor(mx, off, 64));
            float sum = 0.f;
            #pragma unroll
            for (int nt = 0; nt < 4; nt++) {
                float e = __expf(sc[mt][nt][r] - mx);
                sc[mt][nt][r] = e;
                sum += e;
            }
            #pragma unroll
            for (int off = 8; off > 0; off >>= 1) sum += __shfl_xor(sum, off, 64);
            inv[mt][r] = 1.0f / sum;
        }

    // ---- phase 4: O = P.V (per-head P slot in R1, two 32-token k-chunks) ----
    u16* Pl = R1 + w * (64 * PLD);
    f32x4 oc[4][2];
    #pragma unroll
    for (int mt = 0; mt < 4; mt++)
        #pragma unroll
        for (int nd = 0; nd < 2; nd++) oc[mt][nd] = (f32x4){0.f, 0.f, 0.f, 0.f};
    #pragma unroll
    for (int ks = 0; ks < 2; ks++) {
        #pragma unroll
        for (int mt = 0; mt < 4; mt++)
            #pragma unroll
            for (int ntl = 0; ntl < 2; ntl++)
                #pragma unroll
                for (int r = 0; r < 4; r++)
                    Pl[(mt * 16 + lq * 4 + r) * PLD + ntl * 16 + lrow] =
                        f2bf(sc[mt][ks * 2 + ntl][r]);
        bf16x8 vf[2];
        #pragma unroll
        for (int nd = 0; nd < 2; nd++)
            vf[nd] = *(const bf16x8*)&Vt[(w * 32 + nd * 16 + lrow) * VLD + ks * 32 + lq * 8];
        __builtin_amdgcn_s_setprio(1);
        #pragma unroll
        for (int mt = 0; mt < 4; mt++) {
            bf16x8 pf = *(const bf16x8*)&Pl[(mt * 16 + lrow) * PLD + lq * 8];
            #pragma unroll
            for (int nd = 0; nd < 2; nd++)
                oc[mt][nd] = __builtin_amdgcn_mfma_f32_16x16x32_bf16(pf, vf[nd],
                                                                     oc[mt][nd], 0, 0, 0);
        }
        __builtin_amdgcn_s_setprio(0);
    }
    __syncthreads();   // all P reads done; R1 becomes Osh

    // ---- phase 5: stage O (normalized) as 64x192 for proj A-frags ----
    #pragma unroll
    for (int mt = 0; mt < 4; mt++)
        #pragma unroll
        for (int nd = 0; nd < 2; nd++)
            #pragma unroll
            for (int r = 0; r < 4; r++)
                R1[(mt * 16 + lq * 4 + r) * ALD + w * 32 + nd * 16 + lrow] =
                    f2bf(oc[mt][nd][r] * inv[mt][r]);
    __syncthreads();

    // ---- phase 6: proj GEMM (K=192) + roll/reverse + residual -> x1 ----
    f32x4 pacc[4][2];
    #pragma unroll
    for (int mt = 0; mt < 4; mt++)
        #pragma unroll
        for (int nt = 0; nt < 2; nt++) pacc[mt][nt] = (f32x4){0.f, 0.f, 0.f, 0.f};
    const u16* pcol[2];
    #pragma unroll
    for (int nt = 0; nt < 2; nt++)
        pcol[nt] = proj_wT + (size_t)(w * 32 + nt * 16 + lrow) * DIM + lq * 8;
    #pragma unroll
    for (int ks = 0; ks < 6; ks++) {
        bf16x8 af[4];
        #pragma unroll
        for (int mt = 0; mt < 4; mt++)
            af[mt] = *(const bf16x8*)&R1[(mt * 16 + lrow) * ALD + ks * 32 + lq * 8];
        bf16x8 pb[2];
        #pragma unroll
        for (int nt = 0; nt < 2; nt++) pb[nt] = *(const bf16x8*)(pcol[nt] + ks * 32);
        __builtin_amdgcn_s_setprio(1);
        #pragma unroll
        for (int mt = 0; mt < 4; mt++)
            #pragma unroll
            for (int nt = 0; nt < 2; nt++)
                pacc[mt][nt] = __builtin_amdgcn_mfma_f32_16x16x32_bf16(
                    af[mt], pb[nt], pacc[mt][nt], 0, 0, 0);
        __builtin_amdgcn_s_setprio(0);
    }
    float pbias[2];
    #pragma unroll
    for (int nt = 0; nt < 2; nt++) pbias[nt] = proj_b[w * 32 + nt * 16 + lrow];
    #pragma unroll
    for (int mt = 0; mt < 4; mt++)
        #pragma unroll
        for (int r = 0; r < 4; r++) {
            int n = mt * 16 + lq * 4 + r;
            if (n < NTOK) {
                int hi = (wl >> 3) * WS_ + n / WS_;
                int hj = (wl & 7) * WS_ + n % WS_;
                int dh = hi + SHIFT_; if (dh >= HH) dh -= HH;
                int dw = hj + SHIFT_; if (dw >= WW_) dw -= WW_;
                size_t tok = (size_t)(bb * HH * WW_ + dh * WW_ + dw);
                #pragma unroll
                for (int nt = 0; nt < 2; nt++) {
                    int col = w * 32 + nt * 16 + lrow;
                    x1[tok * DIM + col] = x[tok * DIM + col] + pacc[mt][nt][r] + pbias[nt];
                }
            }
        }
}

// ====== fused MLP: fc1 + GELU + fc2 + residual, quarter-H slabs, fc2(h)||fc1(h+1) ======
// 1568 blocks, 384 threads = 6 waves.
// LDS: Ash 64 x ALD (25.6 KB) + Hsh 64 x HLDQ (25.6 KB) = 51.2 KB (UNCHANGED vs r6/r9 —
// residency preserved; round 7's 2x-Hsh variant lost residency and regressed).
// Key change vs round 9: fc2(h) and fc1(h+1) share NO resources (Hsh+W2 vs Ash+W1+regs),
// so they run in ONE phase between the same two barriers — two independent instruction
// streams per phase for the scheduler, no extra LDS. Barriers: 8 -> 7.
// k ascends across passes -> accumulation order identical to monolithic fc2.
__global__ __launch_bounds__(384) void mlp_fused_kernel(
        const u16* __restrict__ h2, const u16* __restrict__ fc1_wT,
        const float* __restrict__ fc1_b, const u16* __restrict__ fc2_wT,
        const float* __restrict__ fc2_b, float* __restrict__ out) {
    __shared__ u16 Ash[MROWS * ALD];
    __shared__ u16 Hsh[MROWS * HLDQ];

    const int tid  = threadIdx.x;
    const int w    = tid >> 6;
    const int lane = tid & 63;
    const int lrow = lane & 15, lq = lane >> 4;
    const int m0   = blockIdx.x * MROWS;

    // ---- stage A tile: 64 rows x 192 = 1536 uint4 ----
    {
        const uint4* src = (const uint4*)(h2 + (size_t)m0 * DIM);
        #pragma unroll
        for (int it = 0; it < 4; it++) {
            int i = tid + it * 384;          // < 1536 = 64*24
            int row = i / 24, c = i - row * 24;
            *(uint4*)&Ash[row * ALD + c * 8] = src[row * 24 + c];
        }
    }
    __syncthreads();

    f32x4 acc2[4][2];
    f32x4 hacc[4][2];
    #pragma unroll
    for (int mt = 0; mt < 4; mt++)
        #pragma unroll
        for (int nt = 0; nt < 2; nt++) {
            acc2[mt][nt] = (f32x4){0.f, 0.f, 0.f, 0.f};
            hacc[mt][nt] = (f32x4){0.f, 0.f, 0.f, 0.f};
        }

    // ---- prologue: fc1 pass 0 -> GELU -> Hsh ----
    {
        const u16* b1base = fc1_wT + (size_t)(w * 32) * DIM;
        #pragma unroll
        for (int ks = 0; ks < 6; ks++) {
            bf16x8 aF[4];
            #pragma unroll
            for (int mt = 0; mt < 4; mt++)
                aF[mt] = *(const bf16x8*)&Ash[(mt * 16 + lrow) * ALD + ks * 32 + lq * 8];
            bf16x8 bF[2];
            #pragma unroll
            for (int nt = 0; nt < 2; nt++)
                bF[nt] = *(const bf16x8*)(b1base + (size_t)(nt * 16 + lrow) * DIM +
                                          ks * 32 + lq * 8);
            __builtin_amdgcn_s_setprio(1);
            #pragma unroll
            for (int mt = 0; mt < 4; mt++)
                #pragma unroll
                for (int nt = 0; nt < 2; nt++)
                    hacc[mt][nt] = __builtin_amdgcn_mfma_f32_16x16x32_bf16(
                        aF[mt], bF[nt], hacc[mt][nt], 0, 0, 0);
            __builtin_amdgcn_s_setprio(0);
        }
        #pragma unroll
        for (int nt = 0; nt < 2; nt++) {
            float bv = fc1_b[w * 32 + nt * 16 + lrow];
            #pragma unroll
            for (int mt = 0; mt < 4; mt++)
                #pragma unroll
                for (int r = 0; r < 4; r++) {
                    float val = hacc[mt][nt][r] + bv;
                    float gel = 0.5f * val * (1.0f + erff(val * 0.70710678118f));
                    Hsh[(mt * 16 + lq * 4 + r) * HLDQ + w * 32 + nt * 16 + lrow] = f2bf(gel);
                }
        }
    }
    __syncthreads();

    // ---- main: per pass, ONE phase = fc2(h) from Hsh || fc1(h+1) from Ash+regs ----
    #pragma unroll
    for (int h = 0; h < 4; h++) {
        if (h < 3) {
            #pragma unroll
            for (int mt = 0; mt < 4; mt++)
                #pragma unroll
                for (int nt = 0; nt < 2; nt++) hacc[mt][nt] = (f32x4){0.f, 0.f, 0.f, 0.f};
        }
        const u16* b1base = fc1_wT + (size_t)((h + 1) * 192 + w * 32) * DIM;
        const u16* b2base = fc2_wT + (size_t)(w * 32) * HIDDEN + h * 192;
        #pragma unroll
        for (int ks = 0; ks < 6; ks++) {
            bf16x8 hF[4];
            #pragma unroll
            for (int mt = 0; mt < 4; mt++)
                hF[mt] = *(const bf16x8*)&Hsh[(mt * 16 + lrow) * HLDQ + ks * 32 + lq * 8];
            bf16x8 b2F[2];
            #pragma unroll
            for (int nt = 0; nt < 2; nt++)
                b2F[nt] = *(const bf16x8*)(b2base + (size_t)(nt * 16 + lrow) * HIDDEN +
                                           ks * 32 + lq * 8);
            bf16x8 aF[4], bF[2];
            if (h < 3) {
                #pragma unroll
                for (int mt = 0; mt < 4; mt++)
                    aF[mt] = *(const bf16x8*)&Ash[(mt * 16 + lrow) * ALD + ks * 32 + lq * 8];
                #pragma unroll
                for (int nt = 0; nt < 2; nt++)
                    bF[nt] = *(const bf16x8*)(b1base + (size_t)(nt * 16 + lrow) * DIM +
                                              ks * 32 + lq * 8);
            }
            __builtin_amdgcn_s_setprio(1);
            #pragma unroll
            for (int mt = 0; mt < 4; mt++)
                #pragma unroll
                for (int nt = 0; nt < 2; nt++)
                    acc2[mt][nt] = __builtin_amdgcn_mfma_f32_16x16x32_bf16(
                        hF[mt], b2F[nt], acc2[mt][nt], 0, 0, 0);
            if (h < 3) {
                #pragma unroll
                for (int mt = 0; mt < 4; mt++)
                    #pragma unroll
                    for (int nt = 0; nt < 2; nt++)
                        hacc[mt][nt] = __builtin_amdgcn_mfma_f32_16x16x32_bf16(
                            aF[mt], bF[nt], hacc[mt][nt], 0, 0, 0);
            }
            __builtin_amdgcn_s_setprio(0);
        }
        __syncthreads();                       // all fc2(h) reads of Hsh complete
        if (h < 3) {
            #pragma unroll
            for (int nt = 0; nt < 2; nt++) {
                float bv = fc1_b[(h + 1) * 192 + w * 32 + nt * 16 + lrow];
                #pragma unroll
                for (int mt = 0; mt < 4; mt++)
                    #pragma unroll
                    for (int r = 0; r < 4; r++) {
                        float val = hacc[mt][nt][r] + bv;
                        float gel = 0.5f * val * (1.0f + erff(val * 0.70710678118f));
                        Hsh[(mt * 16 + lq * 4 + r) * HLDQ + w * 32 + nt * 16 + lrow] =
                            f2bf(gel);
                    }
            }
            __syncthreads();                   // Hsh(h+1) visible to all waves
        }
    }

    // residual RMW into out (rows owned exclusively by this block)
    #pragma unroll
    for (int nt = 0; nt < 2; nt++) {
        int col = w * 32 + nt * 16 + lrow;
        float bv = fc2_b[col];
        #pragma unroll
        for (int mt = 0; mt < 4; mt++)
            #pragma unroll
            for (int r = 0; r < 4; r++) {
                size_t grow = (size_t)(m0 + mt * 16 + lq * 4 + r);
                out[grow * DIM + col] = out[grow * DIM + col] + acc2[mt][nt][r] + bv;
            }
    }
}

extern "C" void kernel_launch(void* const* d_in, const int* in_sizes, int n_in,
                              void* d_out, int out_size, void* d_ws, size_t ws_size,
                              hipStream_t stream) {
    const float* x         = (const float*)d_in[0];
    const float* g1        = (const float*)d_in[1];
    const float* b1        = (const float*)d_in[2];
    const float* qkv_w     = (const float*)d_in[3];
    const float* qkv_b     = (const float*)d_in[4];
    const float* proj_w    = (const float*)d_in[5];
    const float* proj_b    = (const float*)d_in[6];
    const float* rel_table = (const float*)d_in[7];
    const float* g2        = (const float*)d_in[8];
    const float* b2        = (const float*)d_in[9];
    const float* fc1_w     = (const float*)d_in[10];
    const float* fc1_b     = (const float*)d_in[11];
    const float* fc2_w     = (const float*)d_in[12];
    const float* fc2_b     = (const float*)d_in[13];
    const float* attn_mask = (const float*)d_in[14];
    float* out = (float*)d_out;

    const size_t S = (size_t)MTOT * DIM;       // 19,267,584 elements
    u16* wsu = (u16*)d_ws;
    // u16-unit layout (~46 MB total; residual stream lives in d_out)
    u16*   hwin    = wsu;                      // [0,S)    LN1 out -> LN2 out
    u16*   wT      = wsu + S;                  // bf16 transposed weights
    u16*   qkv_wT  = wT;                       // 110592
    u16*   proj_wT = wT + 110592;              // 36864
    u16*   fc1_wT  = wT + 147456;              // 147456
    u16*   fc2_wT  = wT + 294912;              // 147456
    float* tbl     = (float*)(wT + 442368);    // 64*6*64*64 fp32 = 6.29 MB

    // one merged prep launch: 432 transpose + 6144 tbl + 25088 ln1 blocks
    prep_kernel<<<432 + (NWIN * HEADS * 64 * 64) / 256 + MTOT / 4, 256, 0, stream>>>(
        qkv_w, proj_w, fc1_w, fc2_w, qkv_wT, proj_wT, fc1_wT, fc2_wT,
        rel_table, attn_mask, tbl, x, g1, b1, hwin);

    // attn writes residual stream (x + attn) directly into out
    fused_attn_kernel<<<B_ * NWIN, 384, 0, stream>>>(hwin, qkv_wT, qkv_b, proj_wT, proj_b,
                                                     tbl, x, out);
    ln2_kernel<<<MTOT / 4, 256, 0, stream>>>(out, g2, b2, hwin);
    // fused MLP: fc1 + GELU + fc2 + residual, fc2(h)||fc1(h+1) single-phase
    mlp_fused_kernel<<<MTOT / MROWS, 384, 0, stream>>>(hwin, fc1_wT, fc1_b, fc2_wT, fc2_b, out);
}

// Round 11
// 477.619 us; speedup vs baseline: 1.2107x; 1.2107x over previous
//
#include <hip/hip_runtime.h>
#include <math.h>

// ---- problem constants ----
#define B_      32
#define HH      56
#define WW_     56
#define DIM     192
#define WS_     7
#define SHIFT_  3
#define HEADS   6
#define HDIM    32
#define NTOK    49          // WS*WS
#define NWIN    64          // (H/WS)*(W/WS)
#define HIDDEN  768
#define MTOT    (B_*HH*WW_) // 100352 tokens
#define EPS_    1e-5f
#define SCALE_  0.17677669529663687f  // 1/sqrt(32)

// fused-attention LDS strides (u16 units) — round-0 proven values (measured 161 us)
#define ALD 200  // Ash/Qsh/Ksh/Osh row stride (64 rows)
#define PLD 40   // P row stride (per-head 64 rows)
#define VLD 72   // Vt row stride (192 rows)

// fused-MLP geometry (round-6 proven: 183 us): 64 rows/block, quarter-H slab in LDS
#define MROWS 64
#define HLDQ  200  // H quarter-slab row stride (192 + 8 pad); 400 B -> 2-way banks

typedef unsigned short u16;
typedef __attribute__((ext_vector_type(8))) __bf16 bf16x8;
typedef __attribute__((ext_vector_type(4))) float f32x4;

__device__ __forceinline__ float bf2f(u16 u) {
    union { unsigned int i; float f; } c; c.i = ((unsigned int)u) << 16; return c.f;
}
__device__ __forceinline__ u16 f2bf(float f) {
    union { float f; unsigned int i; } c; c.f = f;
    unsigned int x = c.i;
    return (u16)((x + 0x7FFFu + ((x >> 16) & 1u)) >> 16);  // RNE (finite values)
}

__device__ __forceinline__ float wave_sum(float v) {
    #pragma unroll
    for (int off = 32; off > 0; off >>= 1) v += __shfl_xor(v, off, 64);
    return v;
}

// ====== merged prep: 4 weight transposes + bias/mask table + LN1 in ONE launch ======
// Block ranges: [0,108) qkv, [108,144) proj, [144,288) fc1, [288,432) fc2,
// [432,6576) tbl, [6576,31664) ln1+roll+window. Branch is block-uniform.
__global__ __launch_bounds__(256) void prep_kernel(
        const float* __restrict__ qkv_w, const float* __restrict__ proj_w,
        const float* __restrict__ fc1_w, const float* __restrict__ fc2_w,
        u16* __restrict__ qkv_wT, u16* __restrict__ proj_wT,
        u16* __restrict__ fc1_wT, u16* __restrict__ fc2_wT,
        const float* __restrict__ rel_table, const float* __restrict__ mask,
        float* __restrict__ tbl,
        const float* __restrict__ x, const float* __restrict__ g1,
        const float* __restrict__ b1, u16* __restrict__ hwin) {
    __shared__ float t[32][33];
    int b = blockIdx.x;
    if (b >= 6576) {
        // ---- LN1 + roll(-3,-3) + window partition (fp32 in, bf16 out) ----
        int row  = (b - 6576) * 4 + (threadIdx.x >> 6);
        int lane = threadIdx.x & 63;
        int win = row / NTOK;
        int n   = row - win * NTOK;
        int bb  = win >> 6;
        int wl  = win & 63;
        int hi  = (wl >> 3) * WS_ + n / WS_;
        int hj  = (wl & 7) * WS_ + n % WS_;
        int sh = hi + SHIFT_; if (sh >= HH) sh -= HH;
        int sw = hj + SHIFT_; if (sw >= WW_) sw -= WW_;
        const float* xr = x + ((size_t)(bb * HH * WW_ + sh * WW_ + sw)) * DIM;
        float v0 = xr[lane], v1 = xr[lane + 64], v2 = xr[lane + 128];
        float s  = wave_sum(v0 + v1 + v2);
        float sq = wave_sum(v0 * v0 + v1 * v1 + v2 * v2);
        float mu  = s * (1.0f / DIM);
        float var = sq * (1.0f / DIM) - mu * mu;
        float r = rsqrtf(var + EPS_);
        u16* orow = hwin + (size_t)row * DIM;
        orow[lane]       = f2bf((v0 - mu) * r * g1[lane]       + b1[lane]);
        orow[lane + 64]  = f2bf((v1 - mu) * r * g1[lane + 64]  + b1[lane + 64]);
        orow[lane + 128] = f2bf((v2 - mu) * r * g1[lane + 128] + b1[lane + 128]);
        return;
    }
    if (b >= 432) {
        // ---- fused bias+mask table: tbl[((wl*6+head)*64+qi)*64+kj], pads = -1e30 ----
        int idx = (b - 432) * 256 + threadIdx.x;   // < 64*6*4096
        int kj   = idx & 63;
        int qi   = (idx >> 6) & 63;
        int head = (idx >> 12) % 6;
        int wl   = idx / (6 << 12);
        float v;
        if (qi < NTOK && kj < NTOK) {
            int qr = qi / WS_, qc = qi % WS_;
            int kr = kj / WS_, kc = kj % WS_;
            int ri = (qr - kr + 6) * 13 + (qc - kc + 6);
            v = rel_table[ri * HEADS + head] + mask[((size_t)wl * NTOK + qi) * NTOK + kj];
        } else {
            v = -1e30f;
        }
        tbl[idx] = v;
        return;
    }
    const float* W; u16* Wt; int K, N, tb;
    if (b < 108)      { W = qkv_w;  Wt = qkv_wT;  K = DIM;    N = 3 * DIM; tb = b; }
    else if (b < 144) { W = proj_w; Wt = proj_wT; K = DIM;    N = DIM;     tb = b - 108; }
    else if (b < 288) { W = fc1_w;  Wt = fc1_wT;  K = DIM;    N = HIDDEN;  tb = b - 144; }
    else              { W = fc2_w;  Wt = fc2_wT;  K = HIDDEN; N = DIM;     tb = b - 288; }
    // ---- tiled transpose: Wt[n*K+k] = bf16(W[k*N+n]) ----
    int nt32 = N >> 5;
    int bx = tb % nt32;      // n-tile
    int by = tb / nt32;      // k-tile
    int tx = threadIdx.x & 31, ty = threadIdx.x >> 5;   // ty in [0,8)
    #pragma unroll
    for (int i = 0; i < 4; i++)
        t[ty + i * 8][tx] = W[(size_t)(by * 32 + ty + i * 8) * N + bx * 32 + tx];
    __syncthreads();
    #pragma unroll
    for (int i = 0; i < 4; i++)
        Wt[(size_t)(bx * 32 + ty + i * 8) * K + by * 32 + tx] = f2bf(t[tx][ty + i * 8]);
}

// ================= fused window attention: QKV + attn + proj + residual =================
// One block per window (2048), 384 threads = 6 waves = 6 heads.  [measured 161-175 us]
// LDS: R1 [0,15360) u16: Ash/Qsh/Ksh (64xALD) -> P (6 x 64xPLD) -> Osh (64xALD)
//      Vt [15360, 29184): 192 x VLD
// NOTE: no min-waves launch bound (forced 5/EU -> VGPR 48 -> spill disaster, round 2).
// NOTE: LN1/LN2 must NOT be fused in as wave-per-row epilogues (rounds 1 & 5: +60-90 us).
// NOTE: occupancy is register-bound (VGPR+acc); LDS trim to 53760 did not raise it (r3).
// FROZEN (round-6 form).
__global__ __launch_bounds__(384) void fused_attn_kernel(
        const u16* __restrict__ hwin, const u16* __restrict__ qkv_wT,
        const float* __restrict__ qkv_b, const u16* __restrict__ proj_wT,
        const float* __restrict__ proj_b, const float* __restrict__ tbl,
        const float* __restrict__ x, float* __restrict__ x1) {
    __shared__ u16 sm[29184];
    u16* R1 = sm;
    u16* Vt = sm + 15360;

    const int tid  = threadIdx.x;
    const int w    = tid >> 6;       // head
    const int lane = tid & 63;
    const int lrow = lane & 15, lq = lane >> 4;
    const int win  = blockIdx.x;
    const int wl   = win & 63, bb = win >> 6;

    // ---- phase 0: stage LN1 window rows (49x192, zero-pad to 64) ----
    {
        const uint4* src = (const uint4*)(hwin + (size_t)win * NTOK * DIM);
        uint4 z; z.x = z.y = z.z = z.w = 0u;
        #pragma unroll
        for (int it = 0; it < 4; it++) {
            int i = tid + it * 384;          // < 1536 = 64*24
            int row = i / 24, c = i - row * 24;
            uint4 v = (row < NTOK) ? src[row * 24 + c] : z;
            *(uint4*)&R1[row * ALD + c * 8] = v;
        }
    }
    __syncthreads();

    // ---- phase 1: QKV projection for this head (W streamed from L2) ----
    f32x4 acc[3][4][2];
    #pragma unroll
    for (int o = 0; o < 3; o++)
        #pragma unroll
        for (int mt = 0; mt < 4; mt++)
            #pragma unroll
            for (int nt = 0; nt < 2; nt++) acc[o][mt][nt] = (f32x4){0.f, 0.f, 0.f, 0.f};

    const u16* bcol[3][2];
    #pragma unroll
    for (int o = 0; o < 3; o++)
        #pragma unroll
        for (int nt = 0; nt < 2; nt++)
            bcol[o][nt] = qkv_wT + (size_t)(o * DIM + w * 32 + nt * 16 + lrow) * DIM + lq * 8;

    #pragma unroll
    for (int ks = 0; ks < 6; ks++) {
        bf16x8 aF[4];
        #pragma unroll
        for (int mt = 0; mt < 4; mt++)
            aF[mt] = *(const bf16x8*)&R1[(mt * 16 + lrow) * ALD + ks * 32 + lq * 8];
        bf16x8 bF[3][2];
        #pragma unroll
        for (int o = 0; o < 3; o++)
            #pragma unroll
            for (int nt = 0; nt < 2; nt++)
                bF[o][nt] = *(const bf16x8*)(bcol[o][nt] + ks * 32);
        __builtin_amdgcn_s_setprio(1);
        #pragma unroll
        for (int o = 0; o < 3; o++)
            #pragma unroll
            for (int mt = 0; mt < 4; mt++)
                #pragma unroll
                for (int nt = 0; nt < 2; nt++)
                    acc[o][mt][nt] = __builtin_amdgcn_mfma_f32_16x16x32_bf16(
                        aF[mt], bF[o][nt], acc[o][mt][nt], 0, 0, 0);
        __builtin_amdgcn_s_setprio(0);
    }
    // biases
    float bias_[3][2];
    #pragma unroll
    for (int o = 0; o < 3; o++)
        #pragma unroll
        for (int nt = 0; nt < 2; nt++)
            bias_[o][nt] = qkv_b[o * DIM + w * 32 + nt * 16 + lrow];
    #pragma unroll
    for (int o = 0; o < 3; o++)
        #pragma unroll
        for (int mt = 0; mt < 4; mt++)
            #pragma unroll
            for (int nt = 0; nt < 2; nt++)
                #pragma unroll
                for (int r = 0; r < 4; r++) acc[o][mt][nt][r] += bias_[o][nt];

    __syncthreads();   // Ash dead; R1 becomes Q/K staging (wave-local col stripes)

    // ---- phase 2: stage Q (C-layout -> A-frag), then K (-> B-frag), then V^T ----
    #pragma unroll
    for (int mt = 0; mt < 4; mt++)
        #pragma unroll
        for (int nt = 0; nt < 2; nt++)
            #pragma unroll
            for (int r = 0; r < 4; r++)
                R1[(mt * 16 + lq * 4 + r) * ALD + w * 32 + nt * 16 + lrow] =
                    f2bf(acc[0][mt][nt][r]);
    bf16x8 qf[4];
    #pragma unroll
    for (int mt = 0; mt < 4; mt++)
        qf[mt] = *(const bf16x8*)&R1[(mt * 16 + lrow) * ALD + w * 32 + lq * 8];

    #pragma unroll
    for (int mt = 0; mt < 4; mt++)
        #pragma unroll
        for (int nt = 0; nt < 2; nt++)
            #pragma unroll
            for (int r = 0; r < 4; r++)
                R1[(mt * 16 + lq * 4 + r) * ALD + w * 32 + nt * 16 + lrow] =
                    f2bf(acc[1][mt][nt][r]);
    bf16x8 kf[4];
    #pragma unroll
    for (int nt = 0; nt < 4; nt++)
        kf[nt] = *(const bf16x8*)&R1[(nt * 16 + lrow) * ALD + w * 32 + lq * 8];

    #pragma unroll
    for (int mt = 0; mt < 4; mt++)
        #pragma unroll
        for (int nt = 0; nt < 2; nt++)
            #pragma unroll
            for (int r = 0; r < 4; r++)
                Vt[(w * 32 + nt * 16 + lrow) * VLD + mt * 16 + lq * 4 + r] =
                    f2bf(acc[2][mt][nt][r]);

    // ---- phase 3: S = Q.K^T (16 mfma), softmax in registers ----
    f32x4 sc[4][4];
    __builtin_amdgcn_s_setprio(1);
    #pragma unroll
    for (int mt = 0; mt < 4; mt++)
        #pragma unroll
        for (int nt = 0; nt < 4; nt++) {
            f32x4 z = (f32x4){0.f, 0.f, 0.f, 0.f};
            sc[mt][nt] = __builtin_amdgcn_mfma_f32_16x16x32_bf16(qf[mt], kf[nt], z, 0, 0, 0);
        }
    __builtin_amdgcn_s_setprio(0);
    const float* tb = tbl + (((size_t)wl * HEADS + w) << 12);
    float inv[4][4];
    #pragma unroll
    for (int mt = 0; mt < 4; mt++)
        #pragma unroll
        for (int r = 0; r < 4; r++) {
            int qi = mt * 16 + lq * 4 + r;
            float mx = -3.0e38f;
            #pragma unroll
            for (int nt = 0; nt < 4; nt++) {
                float s = sc[mt][nt][r] * SCALE_ + tb[(qi << 6) + nt * 16 + lrow];
                sc[mt][nt][r] = s;
                mx = fmaxf(mx, s);
            }
            #pragma unroll
            for (int off = 8; off > 0; off >>= 1) mx = fmaxf(mx, __shfl_xor(mx, off, 64));
            float sum = 0.f;
            #pragma unroll
            for (int nt = 0; nt < 4; nt++) {
                float e = __expf(sc[mt][nt][r] - mx);
                sc[mt][nt][r] = e;
                sum += e;
            }
            #pragma unroll
            for (int off = 8; off > 0; off >>= 1) sum += __shfl_xor(sum, off, 64);
            inv[mt][r] = 1.0f / sum;
        }

    // ---- phase 4: O = P.V (per-head P slot in R1, two 32-token k-chunks) ----
    u16* Pl = R1 + w * (64 * PLD);
    f32x4 oc[4][2];
    #pragma unroll
    for (int mt = 0; mt < 4; mt++)
        #pragma unroll
        for (int nd = 0; nd < 2; nd++) oc[mt][nd] = (f32x4){0.f, 0.f, 0.f, 0.f};
    #pragma unroll
    for (int ks = 0; ks < 2; ks++) {
        #pragma unroll
        for (int mt = 0; mt < 4; mt++)
            #pragma unroll
            for (int ntl = 0; ntl < 2; ntl++)
                #pragma unroll
                for (int r = 0; r < 4; r++)
                    Pl[(mt * 16 + lq * 4 + r) * PLD + ntl * 16 + lrow] =
                        f2bf(sc[mt][ks * 2 + ntl][r]);
        bf16x8 vf[2];
        #pragma unroll
        for (int nd = 0; nd < 2; nd++)
            vf[nd] = *(const bf16x8*)&Vt[(w * 32 + nd * 16 + lrow) * VLD + ks * 32 + lq * 8];
        __builtin_amdgcn_s_setprio(1);
        #pragma unroll
        for (int mt = 0; mt < 4; mt++) {
            bf16x8 pf = *(const bf16x8*)&Pl[(mt * 16 + lrow) * PLD + lq * 8];
            #pragma unroll
            for (int nd = 0; nd < 2; nd++)
                oc[mt][nd] = __builtin_amdgcn_mfma_f32_16x16x32_bf16(pf, vf[nd],
                                                                     oc[mt][nd], 0, 0, 0);
        }
        __builtin_amdgcn_s_setprio(0);
    }
    __syncthreads();   // all P reads done; R1 becomes Osh

    // ---- phase 5: stage O (normalized) as 64x192 for proj A-frags ----
    #pragma unroll
    for (int mt = 0; mt < 4; mt++)
        #pragma unroll
        for (int nd = 0; nd < 2; nd++)
            #pragma unroll
            for (int r = 0; r < 4; r++)
                R1[(mt * 16 + lq * 4 + r) * ALD + w * 32 + nd * 16 + lrow] =
                    f2bf(oc[mt][nd][r] * inv[mt][r]);
    __syncthreads();

    // ---- phase 6: proj GEMM (K=192) + roll/reverse + residual -> x1 ----
    f32x4 pacc[4][2];
    #pragma unroll
    for (int mt = 0; mt < 4; mt++)
        #pragma unroll
        for (int nt = 0; nt < 2; nt++) pacc[mt][nt] = (f32x4){0.f, 0.f, 0.f, 0.f};
    const u16* pcol[2];
    #pragma unroll
    for (int nt = 0; nt < 2; nt++)
        pcol[nt] = proj_wT + (size_t)(w * 32 + nt * 16 + lrow) * DIM + lq * 8;
    #pragma unroll
    for (int ks = 0; ks < 6; ks++) {
        bf16x8 af[4];
        #pragma unroll
        for (int mt = 0; mt < 4; mt++)
            af[mt] = *(const bf16x8*)&R1[(mt * 16 + lrow) * ALD + ks * 32 + lq * 8];
        bf16x8 pb[2];
        #pragma unroll
        for (int nt = 0; nt < 2; nt++) pb[nt] = *(const bf16x8*)(pcol[nt] + ks * 32);
        __builtin_amdgcn_s_setprio(1);
        #pragma unroll
        for (int mt = 0; mt < 4; mt++)
            #pragma unroll
            for (int nt = 0; nt < 2; nt++)
                pacc[mt][nt] = __builtin_amdgcn_mfma_f32_16x16x32_bf16(
                    af[mt], pb[nt], pacc[mt][nt], 0, 0, 0);
        __builtin_amdgcn_s_setprio(0);
    }
    float pbias[2];
    #pragma unroll
    for (int nt = 0; nt < 2; nt++) pbias[nt] = proj_b[w * 32 + nt * 16 + lrow];
    #pragma unroll
    for (int mt = 0; mt < 4; mt++)
        #pragma unroll
        for (int r = 0; r < 4; r++) {
            int n = mt * 16 + lq * 4 + r;
            if (n < NTOK) {
                int hi = (wl >> 3) * WS_ + n / WS_;
                int hj = (wl & 7) * WS_ + n % WS_;
                int dh = hi + SHIFT_; if (dh >= HH) dh -= HH;
                int dw = hj + SHIFT_; if (dw >= WW_) dw -= WW_;
                size_t tok = (size_t)(bb * HH * WW_ + dh * WW_ + dw);
                #pragma unroll
                for (int nt = 0; nt < 2; nt++) {
                    int col = w * 32 + nt * 16 + lrow;
                    x1[tok * DIM + col] = x[tok * DIM + col] + pacc[mt][nt][r] + pbias[nt];
                }
            }
        }
}

// ====== fused MLP: LN2 + fc1 + GELU + fc2 + residual, quarter-H slabs ======
// [MLP body = round-6 proven form (183 us); round-10's fc2||fc1 merge regressed to 289]
// 1568 blocks, 384 threads = 6 waves.
// LDS: Ash 64 x ALD (25.6 KB) + Hsh 64 x HLDQ (25.6 KB) = 51.2 KB -> 3 blocks/CU.
// NEW: LN2 fused as prologue — block owns rows [m0,m0+64) exclusively, reads the fp32
// residual stream (out) coalesced, LNs in-block, writes bf16 directly to Ash. This
// replaces ln2_kernel (launch + 38.5MB write + 38.5MB read) and the old Ash staging.
// All row loads are issued before any reduction (batched latency — unlike the failed
// scattered wave-per-row LN1-in-attn, these rows are contiguous and block-local).
// NOTE: A staged in LDS (global/L1 A regressed, r8); single Hsh (dbuf regressed, r7).
// k ascends across passes -> accumulation order identical to monolithic fc2.
__global__ __launch_bounds__(384) void mlp_fused_kernel(
        const float* __restrict__ g2, const float* __restrict__ b2,
        const u16* __restrict__ fc1_wT, const float* __restrict__ fc1_b,
        const u16* __restrict__ fc2_wT, const float* __restrict__ fc2_b,
        float* __restrict__ out) {
    __shared__ u16 Ash[MROWS * ALD];
    __shared__ u16 Hsh[MROWS * HLDQ];

    const int tid  = threadIdx.x;
    const int w    = tid >> 6;
    const int lane = tid & 63;
    const int lrow = lane & 15, lq = lane >> 4;
    const int m0   = blockIdx.x * MROWS;

    // ---- LN2 prologue: wave w handles rows w+6k; loads batched ahead of reductions ----
    {
        float gA = g2[lane], gB = g2[lane + 64], gC = g2[lane + 128];
        float bA = b2[lane], bB = b2[lane + 64], bC = b2[lane + 128];
        const float* xrow = out + (size_t)m0 * DIM;
        float va[11][3];
        #pragma unroll
        for (int k = 0; k < 11; k++) {
            int r = w + 6 * k;
            if (r < MROWS) {
                const float* xr = xrow + (size_t)r * DIM;
                va[k][0] = xr[lane];
                va[k][1] = xr[lane + 64];
                va[k][2] = xr[lane + 128];
            }
        }
        #pragma unroll
        for (int k = 0; k < 11; k++) {
            int r = w + 6 * k;
            if (r < MROWS) {
                float s  = wave_sum(va[k][0] + va[k][1] + va[k][2]);
                float sq = wave_sum(va[k][0] * va[k][0] + va[k][1] * va[k][1] +
                                    va[k][2] * va[k][2]);
                float mu  = s * (1.0f / DIM);
                float var = sq * (1.0f / DIM) - mu * mu;
                float rr  = rsqrtf(var + EPS_);
                u16* arow = &Ash[r * ALD];
                arow[lane]       = f2bf((va[k][0] - mu) * rr * gA + bA);
                arow[lane + 64]  = f2bf((va[k][1] - mu) * rr * gB + bB);
                arow[lane + 128] = f2bf((va[k][2] - mu) * rr * gC + bC);
            }
        }
    }
    __syncthreads();

    f32x4 acc2[4][2];
    #pragma unroll
    for (int mt = 0; mt < 4; mt++)
        #pragma unroll
        for (int nt = 0; nt < 2; nt++) acc2[mt][nt] = (f32x4){0.f, 0.f, 0.f, 0.f};

    for (int h = 0; h < 4; h++) {
        // ---- fc1 quarter: 64 x 32 per wave, K=192, W1 streamed from L2 ----
        f32x4 hacc[4][2];
        #pragma unroll
        for (int mt = 0; mt < 4; mt++)
            #pragma unroll
            for (int nt = 0; nt < 2; nt++) hacc[mt][nt] = (f32x4){0.f, 0.f, 0.f, 0.f};
        const u16* b1base = fc1_wT + (size_t)(h * 192 + w * 32) * DIM;
        #pragma unroll
        for (int ks = 0; ks < 6; ks++) {
            bf16x8 aF[4];
            #pragma unroll
            for (int mt = 0; mt < 4; mt++)
                aF[mt] = *(const bf16x8*)&Ash[(mt * 16 + lrow) * ALD + ks * 32 + lq * 8];
            bf16x8 bF[2];
            #pragma unroll
            for (int nt = 0; nt < 2; nt++)
                bF[nt] = *(const bf16x8*)(b1base + (size_t)(nt * 16 + lrow) * DIM +
                                          ks * 32 + lq * 8);
            __builtin_amdgcn_s_setprio(1);
            #pragma unroll
            for (int mt = 0; mt < 4; mt++)
                #pragma unroll
                for (int nt = 0; nt < 2; nt++)
                    hacc[mt][nt] = __builtin_amdgcn_mfma_f32_16x16x32_bf16(
                        aF[mt], bF[nt], hacc[mt][nt], 0, 0, 0);
            __builtin_amdgcn_s_setprio(0);
        }
        if (h) __syncthreads();   // previous pass's fc2 reads of Hsh complete
        // bias + exact GELU -> Hsh quarter-slab (bf16)
        #pragma unroll
        for (int nt = 0; nt < 2; nt++) {
            float bv = fc1_b[h * 192 + w * 32 + nt * 16 + lrow];
            #pragma unroll
            for (int mt = 0; mt < 4; mt++)
                #pragma unroll
                for (int r = 0; r < 4; r++) {
                    float val = hacc[mt][nt][r] + bv;
                    float gel = 0.5f * val * (1.0f + erff(val * 0.70710678118f));
                    Hsh[(mt * 16 + lq * 4 + r) * HLDQ + w * 32 + nt * 16 + lrow] = f2bf(gel);
                }
        }
        __syncthreads();

        // ---- fc2 partial: 64 x 32 per wave, K=192 quarter, W2 streamed from L2 ----
        const u16* b2base = fc2_wT + (size_t)(w * 32) * HIDDEN + h * 192;
        #pragma unroll
        for (int ks = 0; ks < 6; ks++) {
            bf16x8 hF[4];
            #pragma unroll
            for (int mt = 0; mt < 4; mt++)
                hF[mt] = *(const bf16x8*)&Hsh[(mt * 16 + lrow) * HLDQ + ks * 32 + lq * 8];
            bf16x8 b2F[2];
            #pragma unroll
            for (int nt = 0; nt < 2; nt++)
                b2F[nt] = *(const bf16x8*)(b2base + (size_t)(nt * 16 + lrow) * HIDDEN +
                                           ks * 32 + lq * 8);
            __builtin_amdgcn_s_setprio(1);
            #pragma unroll
            for (int mt = 0; mt < 4; mt++)
                #pragma unroll
                for (int nt = 0; nt < 2; nt++)
                    acc2[mt][nt] = __builtin_amdgcn_mfma_f32_16x16x32_bf16(
                        hF[mt], b2F[nt], acc2[mt][nt], 0, 0, 0);
            __builtin_amdgcn_s_setprio(0);
        }
    }

    // residual RMW into out (rows owned exclusively by this block)
    #pragma unroll
    for (int nt = 0; nt < 2; nt++) {
        int col = w * 32 + nt * 16 + lrow;
        float bv = fc2_b[col];
        #pragma unroll
        for (int mt = 0; mt < 4; mt++)
            #pragma unroll
            for (int r = 0; r < 4; r++) {
                size_t grow = (size_t)(m0 + mt * 16 + lq * 4 + r);
                out[grow * DIM + col] = out[grow * DIM + col] + acc2[mt][nt][r] + bv;
            }
    }
}

extern "C" void kernel_launch(void* const* d_in, const int* in_sizes, int n_in,
                              void* d_out, int out_size, void* d_ws, size_t ws_size,
                              hipStream_t stream) {
    const float* x         = (const float*)d_in[0];
    const float* g1        = (const float*)d_in[1];
    const float* b1        = (const float*)d_in[2];
    const float* qkv_w     = (const float*)d_in[3];
    const float* qkv_b     = (const float*)d_in[4];
    const float* proj_w    = (const float*)d_in[5];
    const float* proj_b    = (const float*)d_in[6];
    const float* rel_table = (const float*)d_in[7];
    const float* g2        = (const float*)d_in[8];
    const float* b2        = (const float*)d_in[9];
    const float* fc1_w     = (const float*)d_in[10];
    const float* fc1_b     = (const float*)d_in[11];
    const float* fc2_w     = (const float*)d_in[12];
    const float* fc2_b     = (const float*)d_in[13];
    const float* attn_mask = (const float*)d_in[14];
    float* out = (float*)d_out;

    const size_t S = (size_t)MTOT * DIM;       // 19,267,584 elements
    u16* wsu = (u16*)d_ws;
    // u16-unit layout (~46 MB total; residual stream lives in d_out)
    u16*   hwin    = wsu;                      // [0,S)    LN1 out (window order)
    u16*   wT      = wsu + S;                  // bf16 transposed weights
    u16*   qkv_wT  = wT;                       // 110592
    u16*   proj_wT = wT + 110592;              // 36864
    u16*   fc1_wT  = wT + 147456;              // 147456
    u16*   fc2_wT  = wT + 294912;              // 147456
    float* tbl     = (float*)(wT + 442368);    // 64*6*64*64 fp32 = 6.29 MB

    // one merged prep launch: 432 transpose + 6144 tbl + 25088 ln1 blocks
    prep_kernel<<<432 + (NWIN * HEADS * 64 * 64) / 256 + MTOT / 4, 256, 0, stream>>>(
        qkv_w, proj_w, fc1_w, fc2_w, qkv_wT, proj_wT, fc1_wT, fc2_wT,
        rel_table, attn_mask, tbl, x, g1, b1, hwin);

    // attn writes residual stream (x + attn) directly into out
    fused_attn_kernel<<<B_ * NWIN, 384, 0, stream>>>(hwin, qkv_wT, qkv_b, proj_wT, proj_b,
                                                     tbl, x, out);
    // fused MLP: LN2 + fc1 + GELU + fc2 + residual (reads/writes out in place)
    mlp_fused_kernel<<<MTOT / MROWS, 384, 0, stream>>>(g2, b2, fc1_wT, fc1_b,
                                                       fc2_wT, fc2_b, out);
}

// Round 12
// 474.698 us; speedup vs baseline: 1.2181x; 1.0062x over previous
//
#include <hip/hip_runtime.h>
#include <math.h>

// ---- problem constants ----
#define B_      32
#define HH      56
#define WW_     56
#define DIM     192
#define WS_     7
#define SHIFT_  3
#define HEADS   6
#define HDIM    32
#define NTOK    49          // WS*WS
#define NWIN    64          // (H/WS)*(W/WS)
#define HIDDEN  768
#define MTOT    (B_*HH*WW_) // 100352 tokens
#define EPS_    1e-5f
#define SCALE_  0.17677669529663687f  // 1/sqrt(32)

// fused-attention LDS strides (u16 units) — round-0 proven values
#define ALD 200  // Ash/Qsh/Ksh/Osh row stride (64 rows)
#define PLD 40   // P row stride (per-head 64 rows)
#define VLD 72   // Vt row stride (192 rows)

// fused-MLP geometry (round-6/11 proven): 64 rows/block, quarter-H slab in LDS
#define MROWS 64
#define HLDQ  200  // H quarter-slab row stride (192 + 8 pad); 400 B -> 2-way banks

typedef unsigned short u16;
typedef __attribute__((ext_vector_type(8))) __bf16 bf16x8;
typedef __attribute__((ext_vector_type(4))) float f32x4;

__device__ __forceinline__ float bf2f(u16 u) {
    union { unsigned int i; float f; } c; c.i = ((unsigned int)u) << 16; return c.f;
}
__device__ __forceinline__ u16 f2bf(float f) {
    union { float f; unsigned int i; } c; c.f = f;
    unsigned int x = c.i;
    return (u16)((x + 0x7FFFu + ((x >> 16) & 1u)) >> 16);  // RNE (finite values)
}

__device__ __forceinline__ float wave_sum(float v) {
    #pragma unroll
    for (int off = 32; off > 0; off >>= 1) v += __shfl_xor(v, off, 64);
    return v;
}

// ====== merged prep: 4 weight transposes + bias/mask table in ONE launch ======
// Block ranges: [0,108) qkv, [108,144) proj, [144,288) fc1, [288,432) fc2,
// [432,6576) tbl. (LN1 moved into fused_attn phase 0 — hwin eliminated.)
__global__ __launch_bounds__(256) void prep_kernel(
        const float* __restrict__ qkv_w, const float* __restrict__ proj_w,
        const float* __restrict__ fc1_w, const float* __restrict__ fc2_w,
        u16* __restrict__ qkv_wT, u16* __restrict__ proj_wT,
        u16* __restrict__ fc1_wT, u16* __restrict__ fc2_wT,
        const float* __restrict__ rel_table, const float* __restrict__ mask,
        float* __restrict__ tbl) {
    __shared__ float t[32][33];
    int b = blockIdx.x;
    if (b >= 432) {
        // ---- fused bias+mask table: tbl[((wl*6+head)*64+qi)*64+kj], pads = -1e30 ----
        int idx = (b - 432) * 256 + threadIdx.x;   // < 64*6*4096
        int kj   = idx & 63;
        int qi   = (idx >> 6) & 63;
        int head = (idx >> 12) % 6;
        int wl   = idx / (6 << 12);
        float v;
        if (qi < NTOK && kj < NTOK) {
            int qr = qi / WS_, qc = qi % WS_;
            int kr = kj / WS_, kc = kj % WS_;
            int ri = (qr - kr + 6) * 13 + (qc - kc + 6);
            v = rel_table[ri * HEADS + head] + mask[((size_t)wl * NTOK + qi) * NTOK + kj];
        } else {
            v = -1e30f;
        }
        tbl[idx] = v;
        return;
    }
    const float* W; u16* Wt; int K, N, tb;
    if (b < 108)      { W = qkv_w;  Wt = qkv_wT;  K = DIM;    N = 3 * DIM; tb = b; }
    else if (b < 144) { W = proj_w; Wt = proj_wT; K = DIM;    N = DIM;     tb = b - 108; }
    else if (b < 288) { W = fc1_w;  Wt = fc1_wT;  K = DIM;    N = HIDDEN;  tb = b - 144; }
    else              { W = fc2_w;  Wt = fc2_wT;  K = HIDDEN; N = DIM;     tb = b - 288; }
    // ---- tiled transpose: Wt[n*K+k] = bf16(W[k*N+n]) ----
    int nt32 = N >> 5;
    int bx = tb % nt32;      // n-tile
    int by = tb / nt32;      // k-tile
    int tx = threadIdx.x & 31, ty = threadIdx.x >> 5;   // ty in [0,8)
    #pragma unroll
    for (int i = 0; i < 4; i++)
        t[ty + i * 8][tx] = W[(size_t)(by * 32 + ty + i * 8) * N + bx * 32 + tx];
    __syncthreads();
    #pragma unroll
    for (int i = 0; i < 4; i++)
        Wt[(size_t)(bx * 32 + ty + i * 8) * K + by * 32 + tx] = f2bf(t[tx][ty + i * 8]);
}

// ========== fused window attention: LN1 + QKV + attn + proj + residual ==========
// One block per window (2048), 384 threads = 6 waves = 6 heads.
// LDS: R1 [0,15360) u16: Ash/Qsh/Ksh (64xALD) -> P (6 x 64xPLD) -> Osh (64xALD)
//      Vt [15360, 29184): 192 x VLD
// NEW phase 0: LN1 computed in-block with the round-11-proven BATCHED-load pattern
// (all row loads issued before any reduction — round 1's serial per-row version
// regressed; the batching is the fix under test). Eliminates hwin entirely, and the
// phase-0 x reads pre-warm L2 for phase-6's residual reads of the same rows.
// NOTE: no min-waves launch bound (forced 5/EU -> VGPR 48 -> spill disaster, round 2).
__global__ __launch_bounds__(384) void fused_attn_kernel(
        const u16* __restrict__ qkv_wT, const float* __restrict__ qkv_b,
        const u16* __restrict__ proj_wT, const float* __restrict__ proj_b,
        const float* __restrict__ tbl, const float* __restrict__ x,
        const float* __restrict__ g1, const float* __restrict__ b1,
        float* __restrict__ x1) {
    __shared__ u16 sm[29184];
    u16* R1 = sm;
    u16* Vt = sm + 15360;

    const int tid  = threadIdx.x;
    const int w    = tid >> 6;       // head
    const int lane = tid & 63;
    const int lrow = lane & 15, lq = lane >> 4;
    const int win  = blockIdx.x;
    const int wl   = win & 63, bb = win >> 6;

    // ---- phase 0: LN1 + roll(-3,-3) + window stage, BATCHED loads ----
    {
        float gA = g1[lane], gB = g1[lane + 64], gC = g1[lane + 128];
        float bA = b1[lane], bB = b1[lane + 64], bC = b1[lane + 128];
        float va[11][3];
        #pragma unroll
        for (int k = 0; k < 11; k++) {
            int r = w + 6 * k;
            if (r < NTOK) {
                int hi = (wl >> 3) * WS_ + r / WS_;
                int hj = (wl & 7) * WS_ + r % WS_;
                int sh = hi + SHIFT_; if (sh >= HH) sh -= HH;
                int sw = hj + SHIFT_; if (sw >= WW_) sw -= WW_;
                const float* xr = x + ((size_t)(bb * HH * WW_ + sh * WW_ + sw)) * DIM;
                va[k][0] = xr[lane];
                va[k][1] = xr[lane + 64];
                va[k][2] = xr[lane + 128];
            }
        }
        #pragma unroll
        for (int k = 0; k < 11; k++) {
            int r = w + 6 * k;
            if (r < NTOK) {
                float s  = wave_sum(va[k][0] + va[k][1] + va[k][2]);
                float sq = wave_sum(va[k][0] * va[k][0] + va[k][1] * va[k][1] +
                                    va[k][2] * va[k][2]);
                float mu  = s * (1.0f / DIM);
                float var = sq * (1.0f / DIM) - mu * mu;
                float rr  = rsqrtf(var + EPS_);
                u16* arow = &R1[r * ALD];
                arow[lane]       = f2bf((va[k][0] - mu) * rr * gA + bA);
                arow[lane + 64]  = f2bf((va[k][1] - mu) * rr * gB + bB);
                arow[lane + 128] = f2bf((va[k][2] - mu) * rr * gC + bC);
            } else if (r < 64) {
                u16* arow = &R1[r * ALD];
                arow[lane] = 0; arow[lane + 64] = 0; arow[lane + 128] = 0;
            }
        }
    }
    __syncthreads();

    // ---- phase 1: QKV projection for this head (W streamed from L2) ----
    f32x4 acc[3][4][2];
    #pragma unroll
    for (int o = 0; o < 3; o++)
        #pragma unroll
        for (int mt = 0; mt < 4; mt++)
            #pragma unroll
            for (int nt = 0; nt < 2; nt++) acc[o][mt][nt] = (f32x4){0.f, 0.f, 0.f, 0.f};

    const u16* bcol[3][2];
    #pragma unroll
    for (int o = 0; o < 3; o++)
        #pragma unroll
        for (int nt = 0; nt < 2; nt++)
            bcol[o][nt] = qkv_wT + (size_t)(o * DIM + w * 32 + nt * 16 + lrow) * DIM + lq * 8;

    #pragma unroll
    for (int ks = 0; ks < 6; ks++) {
        bf16x8 aF[4];
        #pragma unroll
        for (int mt = 0; mt < 4; mt++)
            aF[mt] = *(const bf16x8*)&R1[(mt * 16 + lrow) * ALD + ks * 32 + lq * 8];
        bf16x8 bF[3][2];
        #pragma unroll
        for (int o = 0; o < 3; o++)
            #pragma unroll
            for (int nt = 0; nt < 2; nt++)
                bF[o][nt] = *(const bf16x8*)(bcol[o][nt] + ks * 32);
        __builtin_amdgcn_s_setprio(1);
        #pragma unroll
        for (int o = 0; o < 3; o++)
            #pragma unroll
            for (int mt = 0; mt < 4; mt++)
                #pragma unroll
                for (int nt = 0; nt < 2; nt++)
                    acc[o][mt][nt] = __builtin_amdgcn_mfma_f32_16x16x32_bf16(
                        aF[mt], bF[o][nt], acc[o][mt][nt], 0, 0, 0);
        __builtin_amdgcn_s_setprio(0);
    }
    // biases
    float bias_[3][2];
    #pragma unroll
    for (int o = 0; o < 3; o++)
        #pragma unroll
        for (int nt = 0; nt < 2; nt++)
            bias_[o][nt] = qkv_b[o * DIM + w * 32 + nt * 16 + lrow];
    #pragma unroll
    for (int o = 0; o < 3; o++)
        #pragma unroll
        for (int mt = 0; mt < 4; mt++)
            #pragma unroll
            for (int nt = 0; nt < 2; nt++)
                #pragma unroll
                for (int r = 0; r < 4; r++) acc[o][mt][nt][r] += bias_[o][nt];

    __syncthreads();   // Ash dead; R1 becomes Q/K staging (wave-local col stripes)

    // ---- phase 2: stage Q (C-layout -> A-frag), then K (-> B-frag), then V^T ----
    #pragma unroll
    for (int mt = 0; mt < 4; mt++)
        #pragma unroll
        for (int nt = 0; nt < 2; nt++)
            #pragma unroll
            for (int r = 0; r < 4; r++)
                R1[(mt * 16 + lq * 4 + r) * ALD + w * 32 + nt * 16 + lrow] =
                    f2bf(acc[0][mt][nt][r]);
    bf16x8 qf[4];
    #pragma unroll
    for (int mt = 0; mt < 4; mt++)
        qf[mt] = *(const bf16x8*)&R1[(mt * 16 + lrow) * ALD + w * 32 + lq * 8];

    #pragma unroll
    for (int mt = 0; mt < 4; mt++)
        #pragma unroll
        for (int nt = 0; nt < 2; nt++)
            #pragma unroll
            for (int r = 0; r < 4; r++)
                R1[(mt * 16 + lq * 4 + r) * ALD + w * 32 + nt * 16 + lrow] =
                    f2bf(acc[1][mt][nt][r]);
    bf16x8 kf[4];
    #pragma unroll
    for (int nt = 0; nt < 4; nt++)
        kf[nt] = *(const bf16x8*)&R1[(nt * 16 + lrow) * ALD + w * 32 + lq * 8];

    #pragma unroll
    for (int mt = 0; mt < 4; mt++)
        #pragma unroll
        for (int nt = 0; nt < 2; nt++)
            #pragma unroll
            for (int r = 0; r < 4; r++)
                Vt[(w * 32 + nt * 16 + lrow) * VLD + mt * 16 + lq * 4 + r] =
                    f2bf(acc[2][mt][nt][r]);

    // ---- phase 3: S = Q.K^T (16 mfma), softmax in registers ----
    f32x4 sc[4][4];
    __builtin_amdgcn_s_setprio(1);
    #pragma unroll
    for (int mt = 0; mt < 4; mt++)
        #pragma unroll
        for (int nt = 0; nt < 4; nt++) {
            f32x4 z = (f32x4){0.f, 0.f, 0.f, 0.f};
            sc[mt][nt] = __builtin_amdgcn_mfma_f32_16x16x32_bf16(qf[mt], kf[nt], z, 0, 0, 0);
        }
    __builtin_amdgcn_s_setprio(0);
    const float* tb = tbl + (((size_t)wl * HEADS + w) << 12);
    float inv[4][4];
    #pragma unroll
    for (int mt = 0; mt < 4; mt++)
        #pragma unroll
        for (int r = 0; r < 4; r++) {
            int qi = mt * 16 + lq * 4 + r;
            float mx = -3.0e38f;
            #pragma unroll
            for (int nt = 0; nt < 4; nt++) {
                float s = sc[mt][nt][r] * SCALE_ + tb[(qi << 6) + nt * 16 + lrow];
                sc[mt][nt][r] = s;
                mx = fmaxf(mx, s);
            }
            #pragma unroll
            for (int off = 8; off > 0; off >>= 1) mx = fmaxf(mx, __shfl_xor(mx, off, 64));
            float sum = 0.f;
            #pragma unroll
            for (int nt = 0; nt < 4; nt++) {
                float e = __expf(sc[mt][nt][r] - mx);
                sc[mt][nt][r] = e;
                sum += e;
            }
            #pragma unroll
            for (int off = 8; off > 0; off >>= 1) sum += __shfl_xor(sum, off, 64);
            inv[mt][r] = 1.0f / sum;
        }

    // ---- phase 4: O = P.V (per-head P slot in R1, two 32-token k-chunks) ----
    u16* Pl = R1 + w * (64 * PLD);
    f32x4 oc[4][2];
    #pragma unroll
    for (int mt = 0; mt < 4; mt++)
        #pragma unroll
        for (int nd = 0; nd < 2; nd++) oc[mt][nd] = (f32x4){0.f, 0.f, 0.f, 0.f};
    #pragma unroll
    for (int ks = 0; ks < 2; ks++) {
        #pragma unroll
        for (int mt = 0; mt < 4; mt++)
            #pragma unroll
            for (int ntl = 0; ntl < 2; ntl++)
                #pragma unroll
                for (int r = 0; r < 4; r++)
                    Pl[(mt * 16 + lq * 4 + r) * PLD + ntl * 16 + lrow] =
                        f2bf(sc[mt][ks * 2 + ntl][r]);
        bf16x8 vf[2];
        #pragma unroll
        for (int nd = 0; nd < 2; nd++)
            vf[nd] = *(const bf16x8*)&Vt[(w * 32 + nd * 16 + lrow) * VLD + ks * 32 + lq * 8];
        __builtin_amdgcn_s_setprio(1);
        #pragma unroll
        for (int mt = 0; mt < 4; mt++) {
            bf16x8 pf = *(const bf16x8*)&Pl[(mt * 16 + lrow) * PLD + lq * 8];
            #pragma unroll
            for (int nd = 0; nd < 2; nd++)
                oc[mt][nd] = __builtin_amdgcn_mfma_f32_16x16x32_bf16(pf, vf[nd],
                                                                     oc[mt][nd], 0, 0, 0);
        }
        __builtin_amdgcn_s_setprio(0);
    }
    __syncthreads();   // all P reads done; R1 becomes Osh

    // ---- phase 5: stage O (normalized) as 64x192 for proj A-frags ----
    #pragma unroll
    for (int mt = 0; mt < 4; mt++)
        #pragma unroll
        for (int nd = 0; nd < 2; nd++)
            #pragma unroll
            for (int r = 0; r < 4; r++)
                R1[(mt * 16 + lq * 4 + r) * ALD + w * 32 + nd * 16 + lrow] =
                    f2bf(oc[mt][nd][r] * inv[mt][r]);
    __syncthreads();

    // ---- phase 6: proj GEMM (K=192) + roll/reverse + residual -> x1 ----
    f32x4 pacc[4][2];
    #pragma unroll
    for (int mt = 0; mt < 4; mt++)
        #pragma unroll
        for (int nt = 0; nt < 2; nt++) pacc[mt][nt] = (f32x4){0.f, 0.f, 0.f, 0.f};
    const u16* pcol[2];
    #pragma unroll
    for (int nt = 0; nt < 2; nt++)
        pcol[nt] = proj_wT + (size_t)(w * 32 + nt * 16 + lrow) * DIM + lq * 8;
    #pragma unroll
    for (int ks = 0; ks < 6; ks++) {
        bf16x8 af[4];
        #pragma unroll
        for (int mt = 0; mt < 4; mt++)
            af[mt] = *(const bf16x8*)&R1[(mt * 16 + lrow) * ALD + ks * 32 + lq * 8];
        bf16x8 pb[2];
        #pragma unroll
        for (int nt = 0; nt < 2; nt++) pb[nt] = *(const bf16x8*)(pcol[nt] + ks * 32);
        __builtin_amdgcn_s_setprio(1);
        #pragma unroll
        for (int mt = 0; mt < 4; mt++)
            #pragma unroll
            for (int nt = 0; nt < 2; nt++)
                pacc[mt][nt] = __builtin_amdgcn_mfma_f32_16x16x32_bf16(
                    af[mt], pb[nt], pacc[mt][nt], 0, 0, 0);
        __builtin_amdgcn_s_setprio(0);
    }
    float pbias[2];
    #pragma unroll
    for (int nt = 0; nt < 2; nt++) pbias[nt] = proj_b[w * 32 + nt * 16 + lrow];
    #pragma unroll
    for (int mt = 0; mt < 4; mt++)
        #pragma unroll
        for (int r = 0; r < 4; r++) {
            int n = mt * 16 + lq * 4 + r;
            if (n < NTOK) {
                int hi = (wl >> 3) * WS_ + n / WS_;
                int hj = (wl & 7) * WS_ + n % WS_;
                int dh = hi + SHIFT_; if (dh >= HH) dh -= HH;
                int dw = hj + SHIFT_; if (dw >= WW_) dw -= WW_;
                size_t tok = (size_t)(bb * HH * WW_ + dh * WW_ + dw);
                #pragma unroll
                for (int nt = 0; nt < 2; nt++) {
                    int col = w * 32 + nt * 16 + lrow;
                    x1[tok * DIM + col] = x[tok * DIM + col] + pacc[mt][nt][r] + pbias[nt];
                }
            }
        }
}

// ====== fused MLP: LN2 + fc1 + GELU + fc2 + residual, quarter-H slabs ======
// [round-11 proven form: 212 us with LN2 fused]  1568 blocks, 384 threads = 6 waves.
// LDS: Ash 64 x ALD (25.6 KB) + Hsh 64 x HLDQ (25.6 KB) = 51.2 KB -> 3 blocks/CU.
// LN2 prologue: batched row loads (r11 pattern). A staged in LDS (global/L1 A
// regressed, r8); single Hsh (dbuf regressed, r7); no fc2||fc1 merge (regressed, r10).
// k ascends across passes -> accumulation order identical to monolithic fc2.
__global__ __launch_bounds__(384) void mlp_fused_kernel(
        const float* __restrict__ g2, const float* __restrict__ b2,
        const u16* __restrict__ fc1_wT, const float* __restrict__ fc1_b,
        const u16* __restrict__ fc2_wT, const float* __restrict__ fc2_b,
        float* __restrict__ out) {
    __shared__ u16 Ash[MROWS * ALD];
    __shared__ u16 Hsh[MROWS * HLDQ];

    const int tid  = threadIdx.x;
    const int w    = tid >> 6;
    const int lane = tid & 63;
    const int lrow = lane & 15, lq = lane >> 4;
    const int m0   = blockIdx.x * MROWS;

    // ---- LN2 prologue: wave w handles rows w+6k; loads batched ahead of reductions ----
    {
        float gA = g2[lane], gB = g2[lane + 64], gC = g2[lane + 128];
        float bA = b2[lane], bB = b2[lane + 64], bC = b2[lane + 128];
        const float* xrow = out + (size_t)m0 * DIM;
        float va[11][3];
        #pragma unroll
        for (int k = 0; k < 11; k++) {
            int r = w + 6 * k;
            if (r < MROWS) {
                const float* xr = xrow + (size_t)r * DIM;
                va[k][0] = xr[lane];
                va[k][1] = xr[lane + 64];
                va[k][2] = xr[lane + 128];
            }
        }
        #pragma unroll
        for (int k = 0; k < 11; k++) {
            int r = w + 6 * k;
            if (r < MROWS) {
                float s  = wave_sum(va[k][0] + va[k][1] + va[k][2]);
                float sq = wave_sum(va[k][0] * va[k][0] + va[k][1] * va[k][1] +
                                    va[k][2] * va[k][2]);
                float mu  = s * (1.0f / DIM);
                float var = sq * (1.0f / DIM) - mu * mu;
                float rr  = rsqrtf(var + EPS_);
                u16* arow = &Ash[r * ALD];
                arow[lane]       = f2bf((va[k][0] - mu) * rr * gA + bA);
                arow[lane + 64]  = f2bf((va[k][1] - mu) * rr * gB + bB);
                arow[lane + 128] = f2bf((va[k][2] - mu) * rr * gC + bC);
            }
        }
    }
    __syncthreads();

    f32x4 acc2[4][2];
    #pragma unroll
    for (int mt = 0; mt < 4; mt++)
        #pragma unroll
        for (int nt = 0; nt < 2; nt++) acc2[mt][nt] = (f32x4){0.f, 0.f, 0.f, 0.f};

    for (int h = 0; h < 4; h++) {
        // ---- fc1 quarter: 64 x 32 per wave, K=192, W1 streamed from L2 ----
        f32x4 hacc[4][2];
        #pragma unroll
        for (int mt = 0; mt < 4; mt++)
            #pragma unroll
            for (int nt = 0; nt < 2; nt++) hacc[mt][nt] = (f32x4){0.f, 0.f, 0.f, 0.f};
        const u16* b1base = fc1_wT + (size_t)(h * 192 + w * 32) * DIM;
        #pragma unroll
        for (int ks = 0; ks < 6; ks++) {
            bf16x8 aF[4];
            #pragma unroll
            for (int mt = 0; mt < 4; mt++)
                aF[mt] = *(const bf16x8*)&Ash[(mt * 16 + lrow) * ALD + ks * 32 + lq * 8];
            bf16x8 bF[2];
            #pragma unroll
            for (int nt = 0; nt < 2; nt++)
                bF[nt] = *(const bf16x8*)(b1base + (size_t)(nt * 16 + lrow) * DIM +
                                          ks * 32 + lq * 8);
            __builtin_amdgcn_s_setprio(1);
            #pragma unroll
            for (int mt = 0; mt < 4; mt++)
                #pragma unroll
                for (int nt = 0; nt < 2; nt++)
                    hacc[mt][nt] = __builtin_amdgcn_mfma_f32_16x16x32_bf16(
                        aF[mt], bF[nt], hacc[mt][nt], 0, 0, 0);
            __builtin_amdgcn_s_setprio(0);
        }
        if (h) __syncthreads();   // previous pass's fc2 reads of Hsh complete
        // bias + exact GELU -> Hsh quarter-slab (bf16)
        #pragma unroll
        for (int nt = 0; nt < 2; nt++) {
            float bv = fc1_b[h * 192 + w * 32 + nt * 16 + lrow];
            #pragma unroll
            for (int mt = 0; mt < 4; mt++)
                #pragma unroll
                for (int r = 0; r < 4; r++) {
                    float val = hacc[mt][nt][r] + bv;
                    float gel = 0.5f * val * (1.0f + erff(val * 0.70710678118f));
                    Hsh[(mt * 16 + lq * 4 + r) * HLDQ + w * 32 + nt * 16 + lrow] = f2bf(gel);
                }
        }
        __syncthreads();

        // ---- fc2 partial: 64 x 32 per wave, K=192 quarter, W2 streamed from L2 ----
        const u16* b2base = fc2_wT + (size_t)(w * 32) * HIDDEN + h * 192;
        #pragma unroll
        for (int ks = 0; ks < 6; ks++) {
            bf16x8 hF[4];
            #pragma unroll
            for (int mt = 0; mt < 4; mt++)
                hF[mt] = *(const bf16x8*)&Hsh[(mt * 16 + lrow) * HLDQ + ks * 32 + lq * 8];
            bf16x8 b2F[2];
            #pragma unroll
            for (int nt = 0; nt < 2; nt++)
                b2F[nt] = *(const bf16x8*)(b2base + (size_t)(nt * 16 + lrow) * HIDDEN +
                                           ks * 32 + lq * 8);
            __builtin_amdgcn_s_setprio(1);
            #pragma unroll
            for (int mt = 0; mt < 4; mt++)
                #pragma unroll
                for (int nt = 0; nt < 2; nt++)
                    acc2[mt][nt] = __builtin_amdgcn_mfma_f32_16x16x32_bf16(
                        hF[mt], b2F[nt], acc2[mt][nt], 0, 0, 0);
            __builtin_amdgcn_s_setprio(0);
        }
    }

    // residual RMW into out (rows owned exclusively by this block)
    #pragma unroll
    for (int nt = 0; nt < 2; nt++) {
        int col = w * 32 + nt * 16 + lrow;
        float bv = fc2_b[col];
        #pragma unroll
        for (int mt = 0; mt < 4; mt++)
            #pragma unroll
            for (int r = 0; r < 4; r++) {
                size_t grow = (size_t)(m0 + mt * 16 + lq * 4 + r);
                out[grow * DIM + col] = out[grow * DIM + col] + acc2[mt][nt][r] + bv;
            }
    }
}

extern "C" void kernel_launch(void* const* d_in, const int* in_sizes, int n_in,
                              void* d_out, int out_size, void* d_ws, size_t ws_size,
                              hipStream_t stream) {
    const float* x         = (const float*)d_in[0];
    const float* g1        = (const float*)d_in[1];
    const float* b1        = (const float*)d_in[2];
    const float* qkv_w     = (const float*)d_in[3];
    const float* qkv_b     = (const float*)d_in[4];
    const float* proj_w    = (const float*)d_in[5];
    const float* proj_b    = (const float*)d_in[6];
    const float* rel_table = (const float*)d_in[7];
    const float* g2        = (const float*)d_in[8];
    const float* b2        = (const float*)d_in[9];
    const float* fc1_w     = (const float*)d_in[10];
    const float* fc1_b     = (const float*)d_in[11];
    const float* fc2_w     = (const float*)d_in[12];
    const float* fc2_b     = (const float*)d_in[13];
    const float* attn_mask = (const float*)d_in[14];
    float* out = (float*)d_out;

    u16* wsu = (u16*)d_ws;
    // u16-unit layout (~7 MB total; residual stream lives in d_out, no hwin)
    u16*   wT      = wsu;                      // bf16 transposed weights
    u16*   qkv_wT  = wT;                       // 110592
    u16*   proj_wT = wT + 110592;              // 36864
    u16*   fc1_wT  = wT + 147456;              // 147456
    u16*   fc2_wT  = wT + 294912;              // 147456
    float* tbl     = (float*)(wT + 442368);    // 64*6*64*64 fp32 = 6.29 MB

    // one merged prep launch: 432 transpose + 6144 tbl blocks
    prep_kernel<<<432 + (NWIN * HEADS * 64 * 64) / 256, 256, 0, stream>>>(
        qkv_w, proj_w, fc1_w, fc2_w, qkv_wT, proj_wT, fc1_wT, fc2_wT,
        rel_table, attn_mask, tbl);

    // attn: LN1 in-block (batched), writes residual stream (x + attn) into out
    fused_attn_kernel<<<B_ * NWIN, 384, 0, stream>>>(qkv_wT, qkv_b, proj_wT, proj_b,
                                                     tbl, x, g1, b1, out);
    // fused MLP: LN2 + fc1 + GELU + fc2 + residual (reads/writes out in place)
    mlp_fused_kernel<<<MTOT / MROWS, 384, 0, stream>>>(g2, b2, fc1_wT, fc1_b,
                                                       fc2_wT, fc2_b, out);
}